// Round 3
// baseline (859.344 us; speedup 1.0000x reference)
//
#include <hip/hip_runtime.h>
#include <hip/hip_bf16.h>

typedef float f32x4 __attribute__((ext_vector_type(4)));
typedef short s16x8 __attribute__((ext_vector_type(8)));
typedef short s16x4 __attribute__((ext_vector_type(4)));
typedef unsigned short u16;

#define H_ 16
#define E_ 64
#define D_ 1024
#define L_ 2048
#define NQT 32   // 64-row q tiles per (b,h)

__device__ __forceinline__ u16 f2bf(float f) {
  union { float f; unsigned u; } v; v.f = f;
  unsigned u = v.u;
  u += 0x7fffu + ((u >> 16) & 1u);   // round-to-nearest-even
  return (u16)(u >> 16);
}

// out = A (M x K) * W^T + bias,  W is (N x K) row-major.
// A_BF16: A is bf16 (u16) else f32 (converted on the fly).
// PERMUTE: 0 = f32 row-major (M x N); 1 = bf16 (B,H,L,E); 2 = bf16 (B,H,E,L) (V^T).
template<int A_BF16, int PERMUTE>
__global__ __launch_bounds__(256) void gemm_bt(const void* __restrict__ Aptr,
                                               const float* __restrict__ W,
                                               const float* __restrict__ bias,
                                               void* __restrict__ outp,
                                               int M, int N, int K)
{
  __shared__ __align__(16) short As[128][40];   // +8 pad: 80B stride -> 2-way (free)
  __shared__ __align__(16) short Bs[128][40];
  const int tid = threadIdx.x;
  const int m0 = blockIdx.y * 128, n0 = blockIdx.x * 128;
  const int w = tid >> 6, lane = tid & 63, g = lane >> 4, li = lane & 15;
  const int wr = w >> 1, wc = w & 1;

  f32x4 acc[4][4];
#pragma unroll
  for (int i = 0; i < 4; ++i)
#pragma unroll
    for (int j = 0; j < 4; ++j) acc[i][j] = (f32x4){0.f, 0.f, 0.f, 0.f};

  for (int k0 = 0; k0 < K; k0 += 32) {
    __syncthreads();
#pragma unroll
    for (int p = 0; p < 2; ++p) {
      const int c = p * 256 + tid;          // 512 chunks of 8 elems
      const int row = c >> 2, kc = (c & 3) * 8;
      if (A_BF16) {
        const u16* ap = (const u16*)Aptr + (size_t)(m0 + row) * K + k0 + kc;
        *(s16x8*)&As[row][kc] = *(const s16x8*)ap;
      } else {
        const float* ap = (const float*)Aptr + (size_t)(m0 + row) * K + k0 + kc;
        f32x4 f0 = *(const f32x4*)ap, f1 = *(const f32x4*)(ap + 4);
        s16x8 r;
#pragma unroll
        for (int j = 0; j < 4; ++j) { r[j] = (short)f2bf(f0[j]); r[j + 4] = (short)f2bf(f1[j]); }
        *(s16x8*)&As[row][kc] = r;
      }
      const float* wp = W + (size_t)(n0 + row) * K + k0 + kc;
      f32x4 g0 = *(const f32x4*)wp, g1 = *(const f32x4*)(wp + 4);
      s16x8 rb;
#pragma unroll
      for (int j = 0; j < 4; ++j) { rb[j] = (short)f2bf(g0[j]); rb[j + 4] = (short)f2bf(g1[j]); }
      *(s16x8*)&Bs[row][kc] = rb;
    }
    __syncthreads();

    s16x8 a[4], b[4];
#pragma unroll
    for (int mi = 0; mi < 4; ++mi) a[mi] = *(const s16x8*)&As[wr * 64 + mi * 16 + li][g * 8];
#pragma unroll
    for (int ni = 0; ni < 4; ++ni) b[ni] = *(const s16x8*)&Bs[wc * 64 + ni * 16 + li][g * 8];
#pragma unroll
    for (int mi = 0; mi < 4; ++mi)
#pragma unroll
      for (int ni = 0; ni < 4; ++ni)
        acc[mi][ni] = __builtin_amdgcn_mfma_f32_16x16x32_bf16(a[mi], b[ni], acc[mi][ni], 0, 0, 0);
  }

#pragma unroll
  for (int mi = 0; mi < 4; ++mi) {
#pragma unroll
    for (int ni = 0; ni < 4; ++ni) {
      const int row = m0 + wr * 64 + mi * 16 + g * 4;
      const int col = n0 + wc * 64 + ni * 16 + li;
      const float bv = bias[col];
      if (PERMUTE == 2) {
        s16x4 pk;
#pragma unroll
        for (int r = 0; r < 4; ++r) pk[r] = (short)f2bf(acc[mi][ni][r] + bv);
        const int bb = row >> 11, lq = row & (L_ - 1);
        const int hh = col >> 6, e = col & (E_ - 1);
        *(s16x4*)&((u16*)outp)[(((size_t)bb * H_ + hh) * E_ + e) * L_ + lq] = pk;
      } else {
#pragma unroll
        for (int r = 0; r < 4; ++r) {
          const float v = acc[mi][ni][r] + bv;
          const int rr = row + r;
          if (PERMUTE == 1) {
            const int bb = rr >> 11, lq = rr & (L_ - 1);
            const int hh = col >> 6, e = col & (E_ - 1);
            ((u16*)outp)[(((size_t)bb * H_ + hh) * L_ + lq) * E_ + e] = f2bf(v);
          } else {
            ((float*)outp)[(size_t)rr * N + col] = v;
          }
        }
      }
    }
  }
}

// Flash attention, causal. Grid: (NQT, B*H). Block: 256 (4 waves x 16 q rows).
// q,k in (B,H,L,E) bf16; v in (B,H,E,L) bf16 (pre-transposed by V GEMM).
// K/V fragments loaded DIRECTLY from global (L2-resident per bh): no staging
// barriers. Longest blocks (qb=31) dispatch first. 8 blocks/CU target.
__global__ __launch_bounds__(256, 8) void attn_kernel(const u16* __restrict__ qp,
                                                      const u16* __restrict__ kp,
                                                      const u16* __restrict__ vtp,
                                                      u16* __restrict__ op)
{
  __shared__ __align__(16) short Ps[4][16][72];   // per-wave P relayout (no barriers)
  const int tid = threadIdx.x;
  const int bh = blockIdx.y;
  const int w = tid >> 6, lane = tid & 63, g = lane >> 4, li = lane & 15;
  const float scale = 0.125f;                     // 1/sqrt(E)
  const size_t base  = (size_t)bh * L_ * E_;      // q,k: (B,H,L,E)
  const size_t baseT = (size_t)bh * E_ * L_;      // vt:  (B,H,E,L)
  const int bb = bh >> 4, hh = bh & 15;

  const int qb = NQT - 1 - (int)blockIdx.x;       // longest first
  const int qbase = qb * 64;
  const int qrow = qbase + w * 16 + li;
  const u16* qr = qp + base + (size_t)qrow * E_;
  const s16x8 qa0 = *(const s16x8*)(qr + g * 8);
  const s16x8 qa1 = *(const s16x8*)(qr + 32 + g * 8);

  f32x4 o[4];
#pragma unroll
  for (int nc = 0; nc < 4; ++nc) o[nc] = (f32x4){0.f, 0.f, 0.f, 0.f};
  float m_run[4], l_run[4];
#pragma unroll
  for (int r = 0; r < 4; ++r) { m_run[r] = -1e30f; l_run[r] = 0.f; }

  for (int t = 0; t <= qb; ++t) {
    const int kvb = t * 64;
    float s[4][4];   // [kc][r]
#pragma unroll
    for (int kc = 0; kc < 4; ++kc) {
      const u16* krow = kp + base + (size_t)(kvb + kc * 16 + li) * E_;
      const s16x8 k0 = *(const s16x8*)(krow + g * 8);
      const s16x8 k1 = *(const s16x8*)(krow + 32 + g * 8);
      f32x4 sf = (f32x4){0.f, 0.f, 0.f, 0.f};
      sf = __builtin_amdgcn_mfma_f32_16x16x32_bf16(qa0, k0, sf, 0, 0, 0);
      sf = __builtin_amdgcn_mfma_f32_16x16x32_bf16(qa1, k1, sf, 0, 0, 0);
#pragma unroll
      for (int r = 0; r < 4; ++r) s[kc][r] = sf[r] * scale;
    }
    if (t == qb) {   // diagonal tile: causal mask (col > row -> -inf)
#pragma unroll
      for (int kc = 0; kc < 4; ++kc) {
        const int col = kvb + kc * 16 + li;
#pragma unroll
        for (int r = 0; r < 4; ++r) {
          const int rowq = qbase + w * 16 + g * 4 + r;
          if (col > rowq) s[kc][r] = -1e30f;
        }
      }
    }
    // online softmax: a q-row lives across the 16-lane group at fixed reg r
#pragma unroll
    for (int r = 0; r < 4; ++r) {
      float mx = fmaxf(fmaxf(s[0][r], s[1][r]), fmaxf(s[2][r], s[3][r]));
#pragma unroll
      for (int off = 1; off <= 8; off <<= 1) mx = fmaxf(mx, __shfl_xor(mx, off));
      const float mn = fmaxf(m_run[r], mx);
      const float alpha = __expf(m_run[r] - mn);
      m_run[r] = mn;
      float rs = 0.f;
#pragma unroll
      for (int kc = 0; kc < 4; ++kc) { const float pv = __expf(s[kc][r] - mn); s[kc][r] = pv; rs += pv; }
#pragma unroll
      for (int off = 1; off <= 8; off <<= 1) rs += __shfl_xor(rs, off);
      l_run[r] = l_run[r] * alpha + rs;
#pragma unroll
      for (int nc = 0; nc < 4; ++nc) o[nc][r] *= alpha;
    }
    // P (D-layout) -> per-wave LDS -> A-layout fragments (wave-internal, no barrier)
#pragma unroll
    for (int kc = 0; kc < 4; ++kc)
#pragma unroll
      for (int r = 0; r < 4; ++r)
        Ps[w][g * 4 + r][kc * 16 + li] = (short)f2bf(s[kc][r]);
    const s16x8 pa0 = *(const s16x8*)&Ps[w][li][g * 8];
    const s16x8 pa1 = *(const s16x8*)&Ps[w][li][32 + g * 8];
#pragma unroll
    for (int nc = 0; nc < 4; ++nc) {
      const u16* vrow = vtp + baseT + (size_t)(nc * 16 + li) * L_ + kvb;
      const s16x8 v0 = *(const s16x8*)(vrow + g * 8);
      const s16x8 v1 = *(const s16x8*)(vrow + 32 + g * 8);
      o[nc] = __builtin_amdgcn_mfma_f32_16x16x32_bf16(pa0, v0, o[nc], 0, 0, 0);
      o[nc] = __builtin_amdgcn_mfma_f32_16x16x32_bf16(pa1, v1, o[nc], 0, 0, 0);
    }
  }

#pragma unroll
  for (int nc = 0; nc < 4; ++nc) {
#pragma unroll
    for (int r = 0; r < 4; ++r) {
      const int rowq = qbase + w * 16 + g * 4 + r;
      const float v = o[nc][r] / l_run[r];
      op[((size_t)bb * L_ + rowq) * D_ + hh * E_ + nc * 16 + li] = f2bf(v);
    }
  }
}

extern "C" void kernel_launch(void* const* d_in, const int* in_sizes, int n_in,
                              void* d_out, int out_size, void* d_ws, size_t ws_size,
                              hipStream_t stream) {
  const float* queries = (const float*)d_in[0];
  const float* keys    = (const float*)d_in[1];
  const float* values  = (const float*)d_in[2];
  // d_in[3] = attn_mask: exact causal triu(k=1), applied analytically.
  const float* Wq = (const float*)d_in[4];
  const float* bq = (const float*)d_in[5];
  const float* Wk = (const float*)d_in[6];
  const float* bk = (const float*)d_in[7];
  const float* Wv = (const float*)d_in[8];
  const float* bv = (const float*)d_in[9];
  const float* Wo = (const float*)d_in[10];
  const float* bo = (const float*)d_in[11];

  const size_t MD = (size_t)8192 * 1024;
  u16* qbuf = (u16*)d_ws;          // (B,H,L,E) bf16
  u16* kbuf = qbuf + MD;           // (B,H,L,E) bf16
  u16* vbuf = kbuf + MD;           // (B,H,E,L) bf16 (V^T)
  u16* abuf = vbuf + MD;           // attn out (B*L, D) bf16

  dim3 blk(256);
  dim3 ggrid(8, 64);               // (N/128, M/128)
  gemm_bt<0, 1><<<ggrid, blk, 0, stream>>>(queries, Wq, bq, qbuf, 8192, 1024, 1024);
  gemm_bt<0, 1><<<ggrid, blk, 0, stream>>>(keys,    Wk, bk, kbuf, 8192, 1024, 1024);
  gemm_bt<0, 2><<<ggrid, blk, 0, stream>>>(values,  Wv, bv, vbuf, 8192, 1024, 1024);
  attn_kernel<<<dim3(NQT, 64), blk, 0, stream>>>(qbuf, kbuf, vbuf, abuf);
  gemm_bt<1, 0><<<ggrid, blk, 0, stream>>>(abuf, Wo, bo, d_out, 8192, 1024, 1024);
}

// Round 4
// 630.485 us; speedup vs baseline: 1.3630x; 1.3630x over previous
//
#include <hip/hip_runtime.h>
#include <hip/hip_bf16.h>

typedef float f32x4 __attribute__((ext_vector_type(4)));
typedef short s16x8 __attribute__((ext_vector_type(8)));
typedef short s16x4 __attribute__((ext_vector_type(4)));
typedef unsigned short u16;

#define H_ 16
#define E_ 64
#define D_ 1024
#define L_ 2048
#define NQT 32   // 64-row q tiles per (b,h)

__device__ __forceinline__ u16 f2bf(float f) {
  union { float f; unsigned u; } v; v.f = f;
  unsigned u = v.u;
  u += 0x7fffu + ((u >> 16) & 1u);   // round-to-nearest-even
  return (u16)(u >> 16);
}

// out = A (M x K) * W^T + bias,  W is (N x K) row-major.
// A_BF16: A is bf16 (u16) else f32 (converted on the fly).
// PERMUTE: 0 = f32 row-major (M x N); 1 = bf16 (B,H,L,E); 2 = bf16 (B,H,E,L) (V^T).
template<int A_BF16, int PERMUTE>
__global__ __launch_bounds__(256) void gemm_bt(const void* __restrict__ Aptr,
                                               const float* __restrict__ W,
                                               const float* __restrict__ bias,
                                               void* __restrict__ outp,
                                               int M, int N, int K)
{
  __shared__ __align__(16) short As[128][40];   // +8 pad: 80B stride -> 2-way (free)
  __shared__ __align__(16) short Bs[128][40];
  const int tid = threadIdx.x;
  const int m0 = blockIdx.y * 128, n0 = blockIdx.x * 128;
  const int w = tid >> 6, lane = tid & 63, g = lane >> 4, li = lane & 15;
  const int wr = w >> 1, wc = w & 1;

  f32x4 acc[4][4];
#pragma unroll
  for (int i = 0; i < 4; ++i)
#pragma unroll
    for (int j = 0; j < 4; ++j) acc[i][j] = (f32x4){0.f, 0.f, 0.f, 0.f};

  for (int k0 = 0; k0 < K; k0 += 32) {
    __syncthreads();
#pragma unroll
    for (int p = 0; p < 2; ++p) {
      const int c = p * 256 + tid;          // 512 chunks of 8 elems
      const int row = c >> 2, kc = (c & 3) * 8;
      if (A_BF16) {
        const u16* ap = (const u16*)Aptr + (size_t)(m0 + row) * K + k0 + kc;
        *(s16x8*)&As[row][kc] = *(const s16x8*)ap;
      } else {
        const float* ap = (const float*)Aptr + (size_t)(m0 + row) * K + k0 + kc;
        f32x4 f0 = *(const f32x4*)ap, f1 = *(const f32x4*)(ap + 4);
        s16x8 r;
#pragma unroll
        for (int j = 0; j < 4; ++j) { r[j] = (short)f2bf(f0[j]); r[j + 4] = (short)f2bf(f1[j]); }
        *(s16x8*)&As[row][kc] = r;
      }
      const float* wp = W + (size_t)(n0 + row) * K + k0 + kc;
      f32x4 g0 = *(const f32x4*)wp, g1 = *(const f32x4*)(wp + 4);
      s16x8 rb;
#pragma unroll
      for (int j = 0; j < 4; ++j) { rb[j] = (short)f2bf(g0[j]); rb[j + 4] = (short)f2bf(g1[j]); }
      *(s16x8*)&Bs[row][kc] = rb;
    }
    __syncthreads();

    s16x8 a[4], b[4];
#pragma unroll
    for (int mi = 0; mi < 4; ++mi) a[mi] = *(const s16x8*)&As[wr * 64 + mi * 16 + li][g * 8];
#pragma unroll
    for (int ni = 0; ni < 4; ++ni) b[ni] = *(const s16x8*)&Bs[wc * 64 + ni * 16 + li][g * 8];
#pragma unroll
    for (int mi = 0; mi < 4; ++mi)
#pragma unroll
      for (int ni = 0; ni < 4; ++ni)
        acc[mi][ni] = __builtin_amdgcn_mfma_f32_16x16x32_bf16(a[mi], b[ni], acc[mi][ni], 0, 0, 0);
  }

#pragma unroll
  for (int mi = 0; mi < 4; ++mi) {
#pragma unroll
    for (int ni = 0; ni < 4; ++ni) {
      const int row = m0 + wr * 64 + mi * 16 + g * 4;
      const int col = n0 + wc * 64 + ni * 16 + li;
      const float bv = bias[col];
      if (PERMUTE == 2) {
        s16x4 pk;
#pragma unroll
        for (int r = 0; r < 4; ++r) pk[r] = (short)f2bf(acc[mi][ni][r] + bv);
        const int bb = row >> 11, lq = row & (L_ - 1);
        const int hh = col >> 6, e = col & (E_ - 1);
        *(s16x4*)&((u16*)outp)[(((size_t)bb * H_ + hh) * E_ + e) * L_ + lq] = pk;
      } else {
#pragma unroll
        for (int r = 0; r < 4; ++r) {
          const float v = acc[mi][ni][r] + bv;
          const int rr = row + r;
          if (PERMUTE == 1) {
            const int bb = rr >> 11, lq = rr & (L_ - 1);
            const int hh = col >> 6, e = col & (E_ - 1);
            ((u16*)outp)[(((size_t)bb * H_ + hh) * L_ + lq) * E_ + e] = f2bf(v);
          } else {
            ((float*)outp)[(size_t)rr * N + col] = v;
          }
        }
      }
    }
  }
}

// Flash attention, causal. Grid: (NQT, B*H). Block: 256 (4 waves x 16 q rows).
// q,k in (B,H,L,E) bf16; v in (B,H,E,L) bf16 (pre-transposed by V GEMM).
// K/V fragments loaded DIRECTLY from global (L2-resident per bh): no staging,
// no barriers. Longest blocks (qb=31) dispatch first. Softmax in log2 domain.
__global__ __launch_bounds__(256) void attn_kernel(const u16* __restrict__ qp,
                                                   const u16* __restrict__ kp,
                                                   const u16* __restrict__ vtp,
                                                   u16* __restrict__ op)
{
  __shared__ __align__(16) short Ps[4][16][72];   // per-wave P relayout (no barriers)
  const int tid = threadIdx.x;
  const int bh = blockIdx.y;
  const int w = tid >> 6, lane = tid & 63, g = lane >> 4, li = lane & 15;
  const float scl2e = 0.125f * 1.44269504089f;    // (1/sqrt(E)) * log2(e)
  const size_t base  = (size_t)bh * L_ * E_;      // q,k: (B,H,L,E)
  const size_t baseT = (size_t)bh * E_ * L_;      // vt:  (B,H,E,L)
  const int bb = bh >> 4, hh = bh & 15;

  const int qb = NQT - 1 - (int)blockIdx.x;       // longest first
  const int qbase = qb * 64;
  const int qrow = qbase + w * 16 + li;
  const u16* qr = qp + base + (size_t)qrow * E_;
  const s16x8 qa0 = *(const s16x8*)(qr + g * 8);
  const s16x8 qa1 = *(const s16x8*)(qr + 32 + g * 8);

  f32x4 o[4];
#pragma unroll
  for (int nc = 0; nc < 4; ++nc) o[nc] = (f32x4){0.f, 0.f, 0.f, 0.f};
  float m_run[4], l_run[4];
#pragma unroll
  for (int r = 0; r < 4; ++r) { m_run[r] = -1e30f; l_run[r] = 0.f; }

  for (int t = 0; t <= qb; ++t) {
    const int kvb = t * 64;
    float s[4][4];   // [kc][r], log2-domain scores
#pragma unroll
    for (int kc = 0; kc < 4; ++kc) {
      const u16* krow = kp + base + (size_t)(kvb + kc * 16 + li) * E_;
      const s16x8 k0 = *(const s16x8*)(krow + g * 8);
      const s16x8 k1 = *(const s16x8*)(krow + 32 + g * 8);
      f32x4 sf = (f32x4){0.f, 0.f, 0.f, 0.f};
      sf = __builtin_amdgcn_mfma_f32_16x16x32_bf16(qa0, k0, sf, 0, 0, 0);
      sf = __builtin_amdgcn_mfma_f32_16x16x32_bf16(qa1, k1, sf, 0, 0, 0);
#pragma unroll
      for (int r = 0; r < 4; ++r) s[kc][r] = sf[r] * scl2e;
    }
    if (t == qb) {   // diagonal tile: causal mask (col > row -> -inf)
#pragma unroll
      for (int kc = 0; kc < 4; ++kc) {
        const int col = kvb + kc * 16 + li;
#pragma unroll
        for (int r = 0; r < 4; ++r) {
          const int rowq = qbase + w * 16 + g * 4 + r;
          if (col > rowq) s[kc][r] = -1e30f;
        }
      }
    }
    // online softmax (log2 domain): q-row lives across 16-lane group at fixed r
#pragma unroll
    for (int r = 0; r < 4; ++r) {
      float mx = fmaxf(fmaxf(s[0][r], s[1][r]), fmaxf(s[2][r], s[3][r]));
#pragma unroll
      for (int off = 1; off <= 8; off <<= 1) mx = fmaxf(mx, __shfl_xor(mx, off));
      const float mn = fmaxf(m_run[r], mx);
      const float alpha = __builtin_amdgcn_exp2f(m_run[r] - mn);
      m_run[r] = mn;
      float rs = 0.f;
#pragma unroll
      for (int kc = 0; kc < 4; ++kc) {
        const float pv = __builtin_amdgcn_exp2f(s[kc][r] - mn);
        s[kc][r] = pv; rs += pv;
      }
#pragma unroll
      for (int off = 1; off <= 8; off <<= 1) rs += __shfl_xor(rs, off);
      l_run[r] = l_run[r] * alpha + rs;
#pragma unroll
      for (int nc = 0; nc < 4; ++nc) o[nc][r] *= alpha;
    }
    // P (D-layout) -> per-wave LDS -> A-layout fragments (wave-internal, no barrier)
#pragma unroll
    for (int kc = 0; kc < 4; ++kc)
#pragma unroll
      for (int r = 0; r < 4; ++r)
        Ps[w][g * 4 + r][kc * 16 + li] = (short)f2bf(s[kc][r]);
    const s16x8 pa0 = *(const s16x8*)&Ps[w][li][g * 8];
    const s16x8 pa1 = *(const s16x8*)&Ps[w][li][32 + g * 8];
#pragma unroll
    for (int nc = 0; nc < 4; ++nc) {
      const u16* vrow = vtp + baseT + (size_t)(nc * 16 + li) * L_ + kvb;
      const s16x8 v0 = *(const s16x8*)(vrow + g * 8);
      const s16x8 v1 = *(const s16x8*)(vrow + 32 + g * 8);
      o[nc] = __builtin_amdgcn_mfma_f32_16x16x32_bf16(pa0, v0, o[nc], 0, 0, 0);
      o[nc] = __builtin_amdgcn_mfma_f32_16x16x32_bf16(pa1, v1, o[nc], 0, 0, 0);
    }
  }

#pragma unroll
  for (int nc = 0; nc < 4; ++nc) {
#pragma unroll
    for (int r = 0; r < 4; ++r) {
      const int rowq = qbase + w * 16 + g * 4 + r;
      const float v = o[nc][r] / l_run[r];
      op[((size_t)bb * L_ + rowq) * D_ + hh * E_ + nc * 16 + li] = f2bf(v);
    }
  }
}

extern "C" void kernel_launch(void* const* d_in, const int* in_sizes, int n_in,
                              void* d_out, int out_size, void* d_ws, size_t ws_size,
                              hipStream_t stream) {
  const float* queries = (const float*)d_in[0];
  const float* keys    = (const float*)d_in[1];
  const float* values  = (const float*)d_in[2];
  // d_in[3] = attn_mask: exact causal triu(k=1), applied analytically.
  const float* Wq = (const float*)d_in[4];
  const float* bq = (const float*)d_in[5];
  const float* Wk = (const float*)d_in[6];
  const float* bk = (const float*)d_in[7];
  const float* Wv = (const float*)d_in[8];
  const float* bv = (const float*)d_in[9];
  const float* Wo = (const float*)d_in[10];
  const float* bo = (const float*)d_in[11];

  const size_t MD = (size_t)8192 * 1024;
  u16* qbuf = (u16*)d_ws;          // (B,H,L,E) bf16
  u16* kbuf = qbuf + MD;           // (B,H,L,E) bf16
  u16* vbuf = kbuf + MD;           // (B,H,E,L) bf16 (V^T)
  u16* abuf = vbuf + MD;           // attn out (B*L, D) bf16

  dim3 blk(256);
  dim3 ggrid(8, 64);               // (N/128, M/128)
  gemm_bt<0, 1><<<ggrid, blk, 0, stream>>>(queries, Wq, bq, qbuf, 8192, 1024, 1024);
  gemm_bt<0, 1><<<ggrid, blk, 0, stream>>>(keys,    Wk, bk, kbuf, 8192, 1024, 1024);
  gemm_bt<0, 2><<<ggrid, blk, 0, stream>>>(values,  Wv, bv, vbuf, 8192, 1024, 1024);
  attn_kernel<<<dim3(NQT, 64), blk, 0, stream>>>(qbuf, kbuf, vbuf, abuf);
  gemm_bt<1, 0><<<ggrid, blk, 0, stream>>>(abuf, Wo, bo, d_out, 8192, 1024, 1024);
}

// Round 5
// 420.184 us; speedup vs baseline: 2.0452x; 1.5005x over previous
//
#include <hip/hip_runtime.h>
#include <hip/hip_bf16.h>

typedef float f32x4 __attribute__((ext_vector_type(4)));
typedef short s16x8 __attribute__((ext_vector_type(8)));
typedef short s16x4 __attribute__((ext_vector_type(4)));
typedef unsigned short u16;

#define H_ 16
#define E_ 64
#define D_ 1024
#define L_ 2048
#define NQT 32   // 64-row q tiles per (b,h)

__device__ __forceinline__ u16 f2bf(float f) {
  union { float f; unsigned u; } v; v.f = f;
  unsigned u = v.u;
  u += 0x7fffu + ((u >> 16) & 1u);   // round-to-nearest-even
  return (u16)(u >> 16);
}

// out = A (M x K) * W^T + bias,  W is (N x K) row-major.
// A_BF16: A is bf16 (u16) else f32 (converted on the fly).
// PERMUTE: 0 = f32 row-major (M x N); 1 = bf16 (B,H,L,E); 2 = bf16 (B,H,E,L) (V^T).
template<int A_BF16, int PERMUTE>
__global__ __launch_bounds__(256) void gemm_bt(const void* __restrict__ Aptr,
                                               const float* __restrict__ W,
                                               const float* __restrict__ bias,
                                               void* __restrict__ outp,
                                               int M, int N, int K)
{
  __shared__ __align__(16) short As[128][40];   // +8 pad: 80B stride -> 2-way (free)
  __shared__ __align__(16) short Bs[128][40];
  const int tid = threadIdx.x;
  const int m0 = blockIdx.y * 128, n0 = blockIdx.x * 128;
  const int w = tid >> 6, lane = tid & 63, g = lane >> 4, li = lane & 15;
  const int wr = w >> 1, wc = w & 1;

  f32x4 acc[4][4];
#pragma unroll
  for (int i = 0; i < 4; ++i)
#pragma unroll
    for (int j = 0; j < 4; ++j) acc[i][j] = (f32x4){0.f, 0.f, 0.f, 0.f};

  for (int k0 = 0; k0 < K; k0 += 32) {
    __syncthreads();
#pragma unroll
    for (int p = 0; p < 2; ++p) {
      const int c = p * 256 + tid;          // 512 chunks of 8 elems
      const int row = c >> 2, kc = (c & 3) * 8;
      if (A_BF16) {
        const u16* ap = (const u16*)Aptr + (size_t)(m0 + row) * K + k0 + kc;
        *(s16x8*)&As[row][kc] = *(const s16x8*)ap;
      } else {
        const float* ap = (const float*)Aptr + (size_t)(m0 + row) * K + k0 + kc;
        f32x4 f0 = *(const f32x4*)ap, f1 = *(const f32x4*)(ap + 4);
        s16x8 r;
#pragma unroll
        for (int j = 0; j < 4; ++j) { r[j] = (short)f2bf(f0[j]); r[j + 4] = (short)f2bf(f1[j]); }
        *(s16x8*)&As[row][kc] = r;
      }
      const float* wp = W + (size_t)(n0 + row) * K + k0 + kc;
      f32x4 g0 = *(const f32x4*)wp, g1 = *(const f32x4*)(wp + 4);
      s16x8 rb;
#pragma unroll
      for (int j = 0; j < 4; ++j) { rb[j] = (short)f2bf(g0[j]); rb[j + 4] = (short)f2bf(g1[j]); }
      *(s16x8*)&Bs[row][kc] = rb;
    }
    __syncthreads();

    s16x8 a[4], b[4];
#pragma unroll
    for (int mi = 0; mi < 4; ++mi) a[mi] = *(const s16x8*)&As[wr * 64 + mi * 16 + li][g * 8];
#pragma unroll
    for (int ni = 0; ni < 4; ++ni) b[ni] = *(const s16x8*)&Bs[wc * 64 + ni * 16 + li][g * 8];
#pragma unroll
    for (int mi = 0; mi < 4; ++mi)
#pragma unroll
      for (int ni = 0; ni < 4; ++ni)
        acc[mi][ni] = __builtin_amdgcn_mfma_f32_16x16x32_bf16(a[mi], b[ni], acc[mi][ni], 0, 0, 0);
  }

#pragma unroll
  for (int mi = 0; mi < 4; ++mi) {
#pragma unroll
    for (int ni = 0; ni < 4; ++ni) {
      const int row = m0 + wr * 64 + mi * 16 + g * 4;
      const int col = n0 + wc * 64 + ni * 16 + li;
      const float bv = bias[col];
      if (PERMUTE == 2) {
        s16x4 pk;
#pragma unroll
        for (int r = 0; r < 4; ++r) pk[r] = (short)f2bf(acc[mi][ni][r] + bv);
        const int bb = row >> 11, lq = row & (L_ - 1);
        const int hh = col >> 6, e = col & (E_ - 1);
        *(s16x4*)&((u16*)outp)[(((size_t)bb * H_ + hh) * E_ + e) * L_ + lq] = pk;
      } else {
#pragma unroll
        for (int r = 0; r < 4; ++r) {
          const float v = acc[mi][ni][r] + bv;
          const int rr = row + r;
          if (PERMUTE == 1) {
            const int bb = rr >> 11, lq = rr & (L_ - 1);
            const int hh = col >> 6, e = col & (E_ - 1);
            ((u16*)outp)[(((size_t)bb * H_ + hh) * L_ + lq) * E_ + e] = f2bf(v);
          } else {
            ((float*)outp)[(size_t)rr * N + col] = v;
          }
        }
      }
    }
  }
}

// Flash attention, causal. Grid: (NQT/2, B*H). Block: 256 (4 waves x 16 q rows).
// Each block processes q-tiles A=31-x (long) and B=x, SHARING each K/V tile
// load between both. K register-double-buffered (prefetch t+1 during t).
// q,k in (B,H,L,E) bf16; v in (B,H,E,L) bf16. Softmax in log2 domain.
__global__ __launch_bounds__(256) void attn_kernel(const u16* __restrict__ qp,
                                                   const u16* __restrict__ kp,
                                                   const u16* __restrict__ vtp,
                                                   u16* __restrict__ op)
{
  __shared__ __align__(16) short Ps[4][16][72];   // per-wave P relayout (no barriers)
  const int tid = threadIdx.x;
  const int bh = blockIdx.y;
  const int w = tid >> 6, lane = tid & 63, g = lane >> 4, li = lane & 15;
  const float scl2e = 0.125f * 1.44269504089f;    // (1/sqrt(E)) * log2(e)
  const size_t base  = (size_t)bh * L_ * E_;      // q,k: (B,H,L,E)
  const size_t baseT = (size_t)bh * E_ * L_;      // vt:  (B,H,E,L)
  const int bb = bh >> 4, hh = bh & 15;

  const int qbA = NQT - 1 - (int)blockIdx.x;      // 16..31 (long tile)
  const int qbB = (int)blockIdx.x;                // 0..15  (short tile)
  const int qbaseA = qbA * 64, qbaseB = qbB * 64;

  const u16* qrA = qp + base + (size_t)(qbaseA + w * 16 + li) * E_;
  const s16x8 qa0A = *(const s16x8*)(qrA + g * 8);
  const s16x8 qa1A = *(const s16x8*)(qrA + 32 + g * 8);
  const u16* qrB = qp + base + (size_t)(qbaseB + w * 16 + li) * E_;
  const s16x8 qa0B = *(const s16x8*)(qrB + g * 8);
  const s16x8 qa1B = *(const s16x8*)(qrB + 32 + g * 8);

  f32x4 oA[4], oB[4];
  float mA[4], lA[4], mB[4], lB[4];
#pragma unroll
  for (int nc = 0; nc < 4; ++nc) { oA[nc] = (f32x4){0.f,0.f,0.f,0.f}; oB[nc] = (f32x4){0.f,0.f,0.f,0.f}; }
#pragma unroll
  for (int r = 0; r < 4; ++r) { mA[r] = -1e30f; lA[r] = 0.f; mB[r] = -1e30f; lB[r] = 0.f; }

  auto loadk = [&](s16x8* kf, int t) {
    const int kvb = t * 64;
#pragma unroll
    for (int kc = 0; kc < 4; ++kc) {
      const u16* krow = kp + base + (size_t)(kvb + kc * 16 + li) * E_;
      kf[kc * 2]     = *(const s16x8*)(krow + g * 8);
      kf[kc * 2 + 1] = *(const s16x8*)(krow + 32 + g * 8);
    }
  };

  // one q-tile's QK/softmax/PV against tile t (K in kf, V in v0/v1)
  auto attend = [&](int t, const s16x8* kf, const s16x8* v0, const s16x8* v1,
                    const s16x8& q0, const s16x8& q1,
                    f32x4* o, float* m_run, float* l_run, int qb, int qbase) {
    const int kvb = t * 64;
    float s[4][4];   // [kc][r], log2-domain scores
#pragma unroll
    for (int kc = 0; kc < 4; ++kc) {
      f32x4 sf = (f32x4){0.f, 0.f, 0.f, 0.f};
      sf = __builtin_amdgcn_mfma_f32_16x16x32_bf16(q0, kf[kc * 2],     sf, 0, 0, 0);
      sf = __builtin_amdgcn_mfma_f32_16x16x32_bf16(q1, kf[kc * 2 + 1], sf, 0, 0, 0);
#pragma unroll
      for (int r = 0; r < 4; ++r) s[kc][r] = sf[r] * scl2e;
    }
    if (t == qb) {   // diagonal tile: causal mask
#pragma unroll
      for (int kc = 0; kc < 4; ++kc) {
        const int col = kvb + kc * 16 + li;
#pragma unroll
        for (int r = 0; r < 4; ++r) {
          const int rowq = qbase + w * 16 + g * 4 + r;
          if (col > rowq) s[kc][r] = -1e30f;
        }
      }
    }
#pragma unroll
    for (int r = 0; r < 4; ++r) {
      float mx = fmaxf(fmaxf(s[0][r], s[1][r]), fmaxf(s[2][r], s[3][r]));
#pragma unroll
      for (int off = 1; off <= 8; off <<= 1) mx = fmaxf(mx, __shfl_xor(mx, off));
      const float mn = fmaxf(m_run[r], mx);
      const float alpha = __builtin_amdgcn_exp2f(m_run[r] - mn);
      m_run[r] = mn;
      float rs = 0.f;
#pragma unroll
      for (int kc = 0; kc < 4; ++kc) {
        const float pv = __builtin_amdgcn_exp2f(s[kc][r] - mn);
        s[kc][r] = pv; rs += pv;
      }
#pragma unroll
      for (int off = 1; off <= 8; off <<= 1) rs += __shfl_xor(rs, off);
      l_run[r] = l_run[r] * alpha + rs;
#pragma unroll
      for (int nc = 0; nc < 4; ++nc) o[nc][r] *= alpha;
    }
#pragma unroll
    for (int kc = 0; kc < 4; ++kc)
#pragma unroll
      for (int r = 0; r < 4; ++r)
        Ps[w][g * 4 + r][kc * 16 + li] = (short)f2bf(s[kc][r]);
    const s16x8 pa0 = *(const s16x8*)&Ps[w][li][g * 8];
    const s16x8 pa1 = *(const s16x8*)&Ps[w][li][32 + g * 8];
#pragma unroll
    for (int nc = 0; nc < 4; ++nc) {
      o[nc] = __builtin_amdgcn_mfma_f32_16x16x32_bf16(pa0, v0[nc], o[nc], 0, 0, 0);
      o[nc] = __builtin_amdgcn_mfma_f32_16x16x32_bf16(pa1, v1[nc], o[nc], 0, 0, 0);
    }
  };

  // both q-tiles against tile t, sharing K (kf) and V loads
  auto process = [&](int t, const s16x8* kf) {
    const int kvb = t * 64;
    s16x8 v0[4], v1[4];
#pragma unroll
    for (int nc = 0; nc < 4; ++nc) {
      const u16* vrow = vtp + baseT + (size_t)(nc * 16 + li) * L_ + kvb;
      v0[nc] = *(const s16x8*)(vrow + g * 8);
      v1[nc] = *(const s16x8*)(vrow + 32 + g * 8);
    }
    attend(t, kf, v0, v1, qa0A, qa1A, oA, mA, lA, qbA, qbaseA);
    if (t <= qbB)
      attend(t, kf, v0, v1, qa0B, qa1B, oB, mB, lB, qbB, qbaseB);
  };

  s16x8 kfA[8], kfB[8];
  loadk(kfA, 0);
  for (int t = 0; ; t += 2) {
    if (t + 1 <= qbA) loadk(kfB, t + 1);      // prefetch next tile's K
    process(t, kfA);
    if (t + 1 > qbA) break;
    if (t + 2 <= qbA) loadk(kfA, t + 2);      // prefetch t+2
    process(t + 1, kfB);
    if (t + 2 > qbA) break;
  }

  auto epilogue = [&](const f32x4* o, const float* l_run, int qbase) {
#pragma unroll
    for (int nc = 0; nc < 4; ++nc)
#pragma unroll
      for (int r = 0; r < 4; ++r) {
        const int rowq = qbase + w * 16 + g * 4 + r;
        op[((size_t)bb * L_ + rowq) * D_ + hh * E_ + nc * 16 + li] = f2bf(o[nc][r] / l_run[r]);
      }
  };
  epilogue(oA, lA, qbaseA);
  epilogue(oB, lB, qbaseB);
}

extern "C" void kernel_launch(void* const* d_in, const int* in_sizes, int n_in,
                              void* d_out, int out_size, void* d_ws, size_t ws_size,
                              hipStream_t stream) {
  const float* queries = (const float*)d_in[0];
  const float* keys    = (const float*)d_in[1];
  const float* values  = (const float*)d_in[2];
  // d_in[3] = attn_mask: exact causal triu(k=1), applied analytically.
  const float* Wq = (const float*)d_in[4];
  const float* bq = (const float*)d_in[5];
  const float* Wk = (const float*)d_in[6];
  const float* bk = (const float*)d_in[7];
  const float* Wv = (const float*)d_in[8];
  const float* bv = (const float*)d_in[9];
  const float* Wo = (const float*)d_in[10];
  const float* bo = (const float*)d_in[11];

  const size_t MD = (size_t)8192 * 1024;
  u16* qbuf = (u16*)d_ws;          // (B,H,L,E) bf16
  u16* kbuf = qbuf + MD;           // (B,H,L,E) bf16
  u16* vbuf = kbuf + MD;           // (B,H,E,L) bf16 (V^T)
  u16* abuf = vbuf + MD;           // attn out (B*L, D) bf16

  dim3 blk(256);
  dim3 ggrid(8, 64);               // (N/128, M/128)
  gemm_bt<0, 1><<<ggrid, blk, 0, stream>>>(queries, Wq, bq, qbuf, 8192, 1024, 1024);
  gemm_bt<0, 1><<<ggrid, blk, 0, stream>>>(keys,    Wk, bk, kbuf, 8192, 1024, 1024);
  gemm_bt<0, 2><<<ggrid, blk, 0, stream>>>(values,  Wv, bv, vbuf, 8192, 1024, 1024);
  attn_kernel<<<dim3(NQT / 2, 64), blk, 0, stream>>>(qbuf, kbuf, vbuf, abuf);
  gemm_bt<1, 0><<<ggrid, blk, 0, stream>>>(abuf, Wo, bo, d_out, 8192, 1024, 1024);
}

// Round 6
// 410.591 us; speedup vs baseline: 2.0929x; 1.0234x over previous
//
#include <hip/hip_runtime.h>
#include <hip/hip_bf16.h>

typedef float f32x4 __attribute__((ext_vector_type(4)));
typedef short s16x8 __attribute__((ext_vector_type(8)));
typedef short s16x4 __attribute__((ext_vector_type(4)));
typedef unsigned short u16;

#define H_ 16
#define E_ 64
#define D_ 1024
#define L_ 2048
#define NQT 32   // 64-row q tiles per (b,h)

__device__ __forceinline__ u16 f2bf(float f) {
  union { float f; unsigned u; } v; v.f = f;
  unsigned u = v.u;
  u += 0x7fffu + ((u >> 16) & 1u);   // round-to-nearest-even
  return (u16)(u >> 16);
}

// out = A (M x K) * W^T + bias,  W is (N x K) row-major.
// A_BF16: A is bf16 (u16) else f32 (converted on the fly).
// PERMUTE: 0 = f32 row-major (M x N); 1 = bf16 (B,H,L,E); 2 = bf16 (B,H,E,L) (V^T).
template<int A_BF16, int PERMUTE>
__global__ __launch_bounds__(256) void gemm_bt(const void* __restrict__ Aptr,
                                               const float* __restrict__ W,
                                               const float* __restrict__ bias,
                                               void* __restrict__ outp,
                                               int M, int N, int K)
{
  __shared__ __align__(16) short As[128][40];   // +8 pad: 80B stride -> 2-way (free)
  __shared__ __align__(16) short Bs[128][40];
  const int tid = threadIdx.x;
  const int m0 = blockIdx.y * 128, n0 = blockIdx.x * 128;
  const int w = tid >> 6, lane = tid & 63, g = lane >> 4, li = lane & 15;
  const int wr = w >> 1, wc = w & 1;

  f32x4 acc[4][4];
#pragma unroll
  for (int i = 0; i < 4; ++i)
#pragma unroll
    for (int j = 0; j < 4; ++j) acc[i][j] = (f32x4){0.f, 0.f, 0.f, 0.f};

  for (int k0 = 0; k0 < K; k0 += 32) {
    __syncthreads();
#pragma unroll
    for (int p = 0; p < 2; ++p) {
      const int c = p * 256 + tid;          // 512 chunks of 8 elems
      const int row = c >> 2, kc = (c & 3) * 8;
      if (A_BF16) {
        const u16* ap = (const u16*)Aptr + (size_t)(m0 + row) * K + k0 + kc;
        *(s16x8*)&As[row][kc] = *(const s16x8*)ap;
      } else {
        const float* ap = (const float*)Aptr + (size_t)(m0 + row) * K + k0 + kc;
        f32x4 f0 = *(const f32x4*)ap, f1 = *(const f32x4*)(ap + 4);
        s16x8 r;
#pragma unroll
        for (int j = 0; j < 4; ++j) { r[j] = (short)f2bf(f0[j]); r[j + 4] = (short)f2bf(f1[j]); }
        *(s16x8*)&As[row][kc] = r;
      }
      const float* wp = W + (size_t)(n0 + row) * K + k0 + kc;
      f32x4 g0 = *(const f32x4*)wp, g1 = *(const f32x4*)(wp + 4);
      s16x8 rb;
#pragma unroll
      for (int j = 0; j < 4; ++j) { rb[j] = (short)f2bf(g0[j]); rb[j + 4] = (short)f2bf(g1[j]); }
      *(s16x8*)&Bs[row][kc] = rb;
    }
    __syncthreads();

    s16x8 a[4], b[4];
#pragma unroll
    for (int mi = 0; mi < 4; ++mi) a[mi] = *(const s16x8*)&As[wr * 64 + mi * 16 + li][g * 8];
#pragma unroll
    for (int ni = 0; ni < 4; ++ni) b[ni] = *(const s16x8*)&Bs[wc * 64 + ni * 16 + li][g * 8];
#pragma unroll
    for (int mi = 0; mi < 4; ++mi)
#pragma unroll
      for (int ni = 0; ni < 4; ++ni)
        acc[mi][ni] = __builtin_amdgcn_mfma_f32_16x16x32_bf16(a[mi], b[ni], acc[mi][ni], 0, 0, 0);
  }

#pragma unroll
  for (int mi = 0; mi < 4; ++mi) {
#pragma unroll
    for (int ni = 0; ni < 4; ++ni) {
      const int row = m0 + wr * 64 + mi * 16 + g * 4;
      const int col = n0 + wc * 64 + ni * 16 + li;
      const float bv = bias[col];
      if (PERMUTE == 2) {
        s16x4 pk;
#pragma unroll
        for (int r = 0; r < 4; ++r) pk[r] = (short)f2bf(acc[mi][ni][r] + bv);
        const int bb = row >> 11, lq = row & (L_ - 1);
        const int hh = col >> 6, e = col & (E_ - 1);
        *(s16x4*)&((u16*)outp)[(((size_t)bb * H_ + hh) * E_ + e) * L_ + lq] = pk;
      } else {
#pragma unroll
        for (int r = 0; r < 4; ++r) {
          const float v = acc[mi][ni][r] + bv;
          const int rr = row + r;
          if (PERMUTE == 1) {
            const int bb = rr >> 11, lq = rr & (L_ - 1);
            const int hh = col >> 6, e = col & (E_ - 1);
            ((u16*)outp)[(((size_t)bb * H_ + hh) * L_ + lq) * E_ + e] = f2bf(v);
          } else {
            ((float*)outp)[(size_t)rr * N + col] = v;
          }
        }
      }
    }
  }
}

// Flash attention, causal. Grid: (NQT/2, B*H). Block: 256 (4 waves x 16 q rows).
// Swapped QK^T (S^T = K x Q^T) so the k-axis is register-local: row max/sum =
// in-register tree + 2 shfl_xor. Defer-max (THR=8, log2 domain). Each block
// does q-tiles {31-x, x}, sharing K/V tile loads; K reg-double-buffered.
__global__ __launch_bounds__(256) void attn_kernel(const u16* __restrict__ qp,
                                                   const u16* __restrict__ kp,
                                                   const u16* __restrict__ vtp,
                                                   u16* __restrict__ op)
{
  __shared__ __align__(16) short Ps[4][16][72];   // per-wave P relayout
  __shared__ __align__(16) float Bc[4][16];       // per-wave alpha/l broadcast
  const int tid = threadIdx.x;
  const int bh = blockIdx.y;
  const int w = tid >> 6, lane = tid & 63, g = lane >> 4, li = lane & 15;
  const float scl2e = 0.125f * 1.44269504089f;    // (1/sqrt(E)) * log2(e)
  const size_t base  = (size_t)bh * L_ * E_;      // q,k: (B,H,L,E)
  const size_t baseT = (size_t)bh * E_ * L_;      // vt:  (B,H,E,L)
  const int bb = bh >> 4, hh = bh & 15;

  const int qbA = NQT - 1 - (int)blockIdx.x;      // 16..31 (long tile)
  const int qbB = (int)blockIdx.x;                // 0..15  (short tile)
  const int qbaseA = qbA * 64, qbaseB = qbB * 64;

  const u16* qrA = qp + base + (size_t)(qbaseA + w * 16 + li) * E_;
  const s16x8 qa0A = *(const s16x8*)(qrA + g * 8);
  const s16x8 qa1A = *(const s16x8*)(qrA + 32 + g * 8);
  const u16* qrB = qp + base + (size_t)(qbaseB + w * 16 + li) * E_;
  const s16x8 qa0B = *(const s16x8*)(qrB + g * 8);
  const s16x8 qa1B = *(const s16x8*)(qrB + 32 + g * 8);

  f32x4 oA[4], oB[4];
  float mA = -1e30f, lA = 0.f, mB = -1e30f, lB = 0.f;   // per-lane: q = w*16+li
#pragma unroll
  for (int nc = 0; nc < 4; ++nc) { oA[nc] = (f32x4){0.f,0.f,0.f,0.f}; oB[nc] = (f32x4){0.f,0.f,0.f,0.f}; }

  auto loadk = [&](s16x8* kf, int t) {
    const int kvb = t * 64;
#pragma unroll
    for (int kc = 0; kc < 4; ++kc) {
      const u16* krow = kp + base + (size_t)(kvb + kc * 16 + li) * E_;
      kf[kc * 2]     = *(const s16x8*)(krow + g * 8);
      kf[kc * 2 + 1] = *(const s16x8*)(krow + 32 + g * 8);
    }
  };

  // one q-tile against KV tile t. S^T = K*Q^T: lane holds 16 scores of
  // q-row (w*16+li) at k = kvb + kc*16 + g*4 + r.
  auto attend = [&](int t, const s16x8* kf, const s16x8* v0, const s16x8* v1,
                    const s16x8& q0, const s16x8& q1,
                    f32x4* o, float& m_run, float& l_run, int qb, int qbase) {
    const int kvb = t * 64;
    const int qrow = qbase + w * 16 + li;
    float p[4][4];   // [kc][r] log2-domain scores for q-row (w*16+li)
#pragma unroll
    for (int kc = 0; kc < 4; ++kc) {
      f32x4 sf = (f32x4){0.f, 0.f, 0.f, 0.f};
      sf = __builtin_amdgcn_mfma_f32_16x16x32_bf16(kf[kc * 2],     q0, sf, 0, 0, 0);
      sf = __builtin_amdgcn_mfma_f32_16x16x32_bf16(kf[kc * 2 + 1], q1, sf, 0, 0, 0);
#pragma unroll
      for (int r = 0; r < 4; ++r) p[kc][r] = sf[r] * scl2e;
    }
    if (t == qb) {   // diagonal tile: causal mask (k > q -> -inf)
#pragma unroll
      for (int kc = 0; kc < 4; ++kc)
#pragma unroll
        for (int r = 0; r < 4; ++r)
          if (kvb + kc * 16 + g * 4 + r > qrow) p[kc][r] = -1e30f;
    }
    // row max: in-register tree over 16, then cross-g (2 shfls)
    float m0_ = fmaxf(fmaxf(p[0][0], p[0][1]), fmaxf(p[0][2], p[0][3]));
    float m1_ = fmaxf(fmaxf(p[1][0], p[1][1]), fmaxf(p[1][2], p[1][3]));
    float m2_ = fmaxf(fmaxf(p[2][0], p[2][1]), fmaxf(p[2][2], p[2][3]));
    float m3_ = fmaxf(fmaxf(p[3][0], p[3][1]), fmaxf(p[3][2], p[3][3]));
    float mx = fmaxf(fmaxf(m0_, m1_), fmaxf(m2_, m3_));
    mx = fmaxf(mx, __shfl_xor(mx, 16));
    mx = fmaxf(mx, __shfl_xor(mx, 32));
    // defer-max: only rescale when some row grew past threshold (log2: P<=2^8)
    const bool resc = __any(mx > m_run + 8.0f);
    if (resc) {
      const float mn = fmaxf(m_run, mx);
      const float alpha = __builtin_amdgcn_exp2f(m_run - mn);
      m_run = mn;
      if (g == 0) Bc[w][li] = alpha;
      l_run *= alpha;
    }
    float rs = 0.f;
#pragma unroll
    for (int kc = 0; kc < 4; ++kc)
#pragma unroll
      for (int r = 0; r < 4; ++r) {
        const float pv = __builtin_amdgcn_exp2f(p[kc][r] - m_run);
        p[kc][r] = pv; rs += pv;
      }
    rs += __shfl_xor(rs, 16);
    rs += __shfl_xor(rs, 32);
    l_run += rs;
    // pack P^T rows: 4 consecutive k per ds_write_b64
#pragma unroll
    for (int kc = 0; kc < 4; ++kc) {
      s16x4 pk;
#pragma unroll
      for (int r = 0; r < 4; ++r) pk[r] = (short)f2bf(p[kc][r]);
      *(s16x4*)&Ps[w][li][kc * 16 + g * 4] = pk;
    }
    if (resc) {   // rescale O by alpha of its rows (broadcast via LDS)
      const f32x4 av = *(const f32x4*)&Bc[w][g * 4];
#pragma unroll
      for (int nc = 0; nc < 4; ++nc)
#pragma unroll
        for (int r = 0; r < 4; ++r) o[nc][r] *= av[r];
    }
    const s16x8 pa0 = *(const s16x8*)&Ps[w][li][g * 8];
    const s16x8 pa1 = *(const s16x8*)&Ps[w][li][32 + g * 8];
#pragma unroll
    for (int nc = 0; nc < 4; ++nc) {
      o[nc] = __builtin_amdgcn_mfma_f32_16x16x32_bf16(pa0, v0[nc], o[nc], 0, 0, 0);
      o[nc] = __builtin_amdgcn_mfma_f32_16x16x32_bf16(pa1, v1[nc], o[nc], 0, 0, 0);
    }
  };

  // both q-tiles against tile t, sharing K (kf) and V loads
  auto process = [&](int t, const s16x8* kf) {
    const int kvb = t * 64;
    s16x8 v0[4], v1[4];
#pragma unroll
    for (int nc = 0; nc < 4; ++nc) {
      const u16* vrow = vtp + baseT + (size_t)(nc * 16 + li) * L_ + kvb;
      v0[nc] = *(const s16x8*)(vrow + g * 8);
      v1[nc] = *(const s16x8*)(vrow + 32 + g * 8);
    }
    attend(t, kf, v0, v1, qa0A, qa1A, oA, mA, lA, qbA, qbaseA);
    if (t <= qbB)
      attend(t, kf, v0, v1, qa0B, qa1B, oB, mB, lB, qbB, qbaseB);
  };

  s16x8 kfA[8], kfB[8];
  loadk(kfA, 0);
  for (int t = 0; ; t += 2) {
    if (t + 1 <= qbA) loadk(kfB, t + 1);      // prefetch next tile's K
    process(t, kfA);
    if (t + 1 > qbA) break;
    if (t + 2 <= qbA) loadk(kfA, t + 2);      // prefetch t+2
    process(t + 1, kfB);
    if (t + 2 > qbA) break;
  }

  auto epilogue = [&](const f32x4* o, float l_run, int qbase) {
    if (g == 0) Bc[w][li] = l_run;            // broadcast l to output rows
    const f32x4 lv = *(const f32x4*)&Bc[w][g * 4];
    f32x4 inv;
#pragma unroll
    for (int r = 0; r < 4; ++r) inv[r] = 1.0f / lv[r];
#pragma unroll
    for (int nc = 0; nc < 4; ++nc)
#pragma unroll
      for (int r = 0; r < 4; ++r) {
        const int rowq = qbase + w * 16 + g * 4 + r;
        op[((size_t)bb * L_ + rowq) * D_ + hh * E_ + nc * 16 + li] = f2bf(o[nc][r] * inv[r]);
      }
  };
  epilogue(oA, lA, qbaseA);
  epilogue(oB, lB, qbaseB);
}

extern "C" void kernel_launch(void* const* d_in, const int* in_sizes, int n_in,
                              void* d_out, int out_size, void* d_ws, size_t ws_size,
                              hipStream_t stream) {
  const float* queries = (const float*)d_in[0];
  const float* keys    = (const float*)d_in[1];
  const float* values  = (const float*)d_in[2];
  // d_in[3] = attn_mask: exact causal triu(k=1), applied analytically.
  const float* Wq = (const float*)d_in[4];
  const float* bq = (const float*)d_in[5];
  const float* Wk = (const float*)d_in[6];
  const float* bk = (const float*)d_in[7];
  const float* Wv = (const float*)d_in[8];
  const float* bv = (const float*)d_in[9];
  const float* Wo = (const float*)d_in[10];
  const float* bo = (const float*)d_in[11];

  const size_t MD = (size_t)8192 * 1024;
  u16* qbuf = (u16*)d_ws;          // (B,H,L,E) bf16
  u16* kbuf = qbuf + MD;           // (B,H,L,E) bf16
  u16* vbuf = kbuf + MD;           // (B,H,E,L) bf16 (V^T)
  u16* abuf = vbuf + MD;           // attn out (B*L, D) bf16

  dim3 blk(256);
  dim3 ggrid(8, 64);               // (N/128, M/128)
  gemm_bt<0, 1><<<ggrid, blk, 0, stream>>>(queries, Wq, bq, qbuf, 8192, 1024, 1024);
  gemm_bt<0, 1><<<ggrid, blk, 0, stream>>>(keys,    Wk, bk, kbuf, 8192, 1024, 1024);
  gemm_bt<0, 2><<<ggrid, blk, 0, stream>>>(values,  Wv, bv, vbuf, 8192, 1024, 1024);
  attn_kernel<<<dim3(NQT / 2, 64), blk, 0, stream>>>(qbuf, kbuf, vbuf, abuf);
  gemm_bt<1, 0><<<ggrid, blk, 0, stream>>>(abuf, Wo, bo, d_out, 8192, 1024, 1024);
}